// Round 6
// baseline (187.820 us; speedup 1.0000x reference)
//
#include <hip/hip_runtime.h>

typedef __attribute__((ext_vector_type(8))) __bf16 bf16x8;
typedef __attribute__((ext_vector_type(4))) __bf16 bf16x4;
typedef __attribute__((ext_vector_type(4))) float f32x4;
typedef __attribute__((ext_vector_type(16))) float f32x16;
typedef __attribute__((ext_vector_type(8))) unsigned short us8;
typedef __attribute__((ext_vector_type(4))) unsigned int u32x4;

constexpr float SCALE_L2E = 0.08838834764831845f * 1.4426950408889634f; // (1/sqrt(128))*log2(e)

__device__ __forceinline__ unsigned short f2bf(float f) {
  unsigned int u = __float_as_uint(f);
  u = (u + 0x7FFFu + ((u >> 16) & 1u)) >> 16;
  return (unsigned short)u;
}

__device__ __forceinline__ void gl_lds16(const void* g, void* l) {
  __builtin_amdgcn_global_load_lds(
      (__attribute__((address_space(1))) void*)const_cast<void*>(g),
      (__attribute__((address_space(3))) void*)l, 16, 0, 0);
}

// ---------------- K0: f32 -> bf16 convert (query + 3 weight matrices) ----------------
__global__ __launch_bounds__(256) void k_convert(
    const float* __restrict__ q, const float* __restrict__ wq,
    const float* __restrict__ wk, const float* __restrict__ wv,
    unsigned short* __restrict__ xb, unsigned short* __restrict__ wb) {
  long i = ((long)blockIdx.x * 256 + threadIdx.x) * 8;
  const float* s; unsigned short* d;
  if (i < 4194304)      { s = q  + i;             d = xb + i; }
  else if (i < 5242880) { s = wq + (i - 4194304); d = wb + (i - 4194304); }
  else if (i < 6291456) { s = wk + (i - 5242880); d = wb + 1048576 + (i - 5242880); }
  else                  { s = wv + (i - 6291456); d = wb + 2097152 + (i - 6291456); }
  float4 a = *(const float4*)s;
  float4 b = *(const float4*)(s + 4);
  us8 r;
  r[0]=f2bf(a.x); r[1]=f2bf(a.y); r[2]=f2bf(a.z); r[3]=f2bf(a.w);
  r[4]=f2bf(b.x); r[5]=f2bf(b.y); r[6]=f2bf(b.z); r[7]=f2bf(b.w);
  *(us8*)d = r;
}

// ---------------- K1: projection GEMM  C = X @ W^T + b  (z selects q/k/v) ----------------
// z==0 (q): sign twist, row-major out. z==1 (k): row-major out (repacked later).
// z==2 (v): written DIRECTLY in PV A-fragment order:
//   vfrag[bh][dt][mc][lane][j]  where lane=(d&31)+32*((m>>3)&1), j=m&7, dt=d>>5, mc=m>>4.
__global__ __launch_bounds__(256) void k_proj(
    const unsigned short* __restrict__ xb, const unsigned short* __restrict__ wb,
    const float* __restrict__ bq, const float* __restrict__ bk, const float* __restrict__ bv,
    unsigned short* __restrict__ oq, unsigned short* __restrict__ ok_, unsigned short* __restrict__ vt) {
  __shared__ unsigned short As[4096]; // 128 rows x 32 k
  __shared__ unsigned short Bs[4096];
  const int t = threadIdx.x;
  const int wave = t >> 6, lane = t & 63;
  const int lrow = lane & 15, grp = lane >> 4;
  const int z = blockIdx.z;
  const unsigned short* w = wb + (size_t)z * 1048576;
  const float* bias = (z == 0) ? bq : ((z == 1) ? bk : bv);

  const unsigned short* asrc = xb + ((size_t)(blockIdx.y * 128 + (t >> 2)) * 1024 + (t & 3) * 8);
  const unsigned short* bsrc = w  + ((size_t)(blockIdx.x * 128 + (t >> 2)) * 1024 + (t & 3) * 8);

  f32x4 acc[4][4] = {};
  for (int kt = 0; kt < 32; ++kt) {
    gl_lds16(asrc + kt*32,              &As[t*8]);
    gl_lds16(asrc + kt*32 + 64*1024,    &As[2048 + t*8]);
    gl_lds16(bsrc + kt*32,              &Bs[t*8]);
    gl_lds16(bsrc + kt*32 + 64*1024,    &Bs[2048 + t*8]);
    __syncthreads();
    const int wr = wave >> 1, wc = wave & 1;
    bf16x8 af[4], bf[4];
#pragma unroll
    for (int mf = 0; mf < 4; ++mf)
      af[mf] = *(const bf16x8*)&As[(wr*64 + mf*16 + lrow)*32 + grp*8];
#pragma unroll
    for (int nf = 0; nf < 4; ++nf)
      bf[nf] = *(const bf16x8*)&Bs[(wc*64 + nf*16 + lrow)*32 + grp*8];
#pragma unroll
    for (int mf = 0; mf < 4; ++mf)
#pragma unroll
      for (int nf = 0; nf < 4; ++nf)
        acc[mf][nf] = __builtin_amdgcn_mfma_f32_16x16x32_bf16(af[mf], bf[nf], acc[mf][nf], 0, 0, 0);
    __syncthreads();
  }
  const int wr = wave >> 1, wc = wave & 1;
  if (z == 2) {
#pragma unroll
    for (int nf = 0; nf < 4; ++nf) {
      const int col = blockIdx.x*128 + wc*64 + nf*16 + lrow;   // global channel (h,d)
      const int h = col >> 7, dd = col & 127;
      const int dt = dd >> 5, lv = dd & 31;
      const float bsv = bias[col];
#pragma unroll
      for (int mf = 0; mf < 4; ++mf) {
        const int r0 = blockIdx.y*128 + wr*64 + mf*16 + grp*4;
        const int bb = r0 >> 11, m = r0 & 2047;
        const int mc = m >> 4, him = (m >> 3) & 1, j0 = m & 7;
        bf16x4 pv;
#pragma unroll
        for (int i = 0; i < 4; ++i) pv[i] = (__bf16)(acc[mf][nf][i] + bsv);
        const size_t off = ((((size_t)((bb*8 + h)*4 + dt))*128 + mc)*64 + lv + 32*him)*8 + j0;
        *(bf16x4*)&vt[off] = pv;
      }
    }
  } else {
    unsigned short* dst = (z == 0) ? oq : ok_;
    const float sign = (z == 0 && (lane & 7) >= 4) ? -1.0f : 1.0f;
#pragma unroll
    for (int nf = 0; nf < 4; ++nf) {
      const int col = blockIdx.x*128 + wc*64 + nf*16 + lrow;
      const float bsv = bias[col];
#pragma unroll
      for (int mf = 0; mf < 4; ++mf)
#pragma unroll
        for (int i = 0; i < 4; ++i) {
          const int row = blockIdx.y*128 + wr*64 + mf*16 + grp*4 + i;
          dst[(size_t)row*1024 + col] = f2bf((acc[mf][nf][i] + bsv) * sign);
        }
    }
  }
}

// ---------------- K2: repack K row-major -> QK A-fragment order ----------------
// kfrag[bh][mtile][kc][lane][j]: lane=(m&31)+32*((k>>3)&1), j=k&7, mtile=m>>5, kc=k>>4.
__global__ __launch_bounds__(256) void k_repack(const unsigned short* __restrict__ kws,
                                                unsigned short* __restrict__ kfrag) {
  const int c = blockIdx.x * 256 + threadIdx.x;   // 0..524287 (us8 chunks)
  const int lane = c & 63, kc = (c >> 6) & 7, mtile = (c >> 9) & 63, bh = c >> 15;
  const int b = bh >> 3, h = bh & 7;
  const int m = mtile*32 + (lane & 31);
  const int kd = kc*16 + (lane >> 5)*8;
  us8 v = *(const us8*)&kws[((size_t)(b*2048 + m))*1024 + h*128 + kd];
  *(us8*)&kfrag[(size_t)c * 8] = v;
}

// ---------------- K3: fused attention out + rowsum (barrier-free main loop) ----------------
// 256 blocks x 512 thr (8 waves). Block = (bh, 128 q-rows). Waves: mg = wave>>2 (m-half),
// lg = wave&3 (32-l slice). 32x32x16 MFMA; swapped QK (S^T = mfma(K,Q)); P stays in
// registers via cvt_pk_bf16 + permlane32_swap (T12); PV = mfma(V^T_frag, P_frag) -> out^T.
__global__ __launch_bounds__(512) void k_attn_out(
    const unsigned short* __restrict__ qw, const unsigned short* __restrict__ kfrag,
    const unsigned short* __restrict__ vfrag, float* __restrict__ outp,
    float* __restrict__ rsw) {
  __shared__ float slab[8][32][36];   // 36 KB, padded
  __shared__ float rsred[8][32];
  __shared__ float invb[128];

  const int bid = blockIdx.x;
  const int xcd = bid & 7, r_ = bid >> 3;
  const int bh = (xcd << 1) | (r_ & 1);    // 2 bh per XCD -> K/V L2-resident
  const int lt = r_ >> 1;                  // 0..15 (128-l tile)
  const int b = bh >> 3, h = bh & 7;
  const int t = threadIdx.x;
  const int wave = t >> 6, lane = t & 63;
  const int mg = wave >> 2, lg = wave & 3;
  const int lm = lane & 31, hi = lane >> 5;

  // Q fragments (B-operand: col = lane&31 = l, k = kc*16 + 8*hi + j). Loaded once.
  bf16x8 qf[8];
  {
    const unsigned short* qp = qw + ((size_t)(b*2048 + lt*128 + lg*32 + lm))*1024
                                  + (size_t)h*128 + hi*8;   // FIX: head offset
#pragma unroll
    for (int kc = 0; kc < 8; ++kc) qf[kc] = *(const bf16x8*)(qp + kc*16);
  }

  const unsigned short* kbase = kfrag + (size_t)bh*262144 + (size_t)mg*32*4096 + lane*8;
  const unsigned short* vbase = vfrag + (size_t)bh*262144 + (size_t)mg*64*512  + lane*8;

  f32x16 oacc[4] = {};
  float rs = 0.f;

#pragma unroll 2
  for (int it = 0; it < 32; ++it) {
    bf16x8 kf[8];
#pragma unroll
    for (int kc = 0; kc < 8; ++kc)
      kf[kc] = *(const bf16x8*)(kbase + it*4096 + kc*512);
    f32x16 s = {};
#pragma unroll
    for (int kc = 0; kc < 8; ++kc)
      s = __builtin_amdgcn_mfma_f32_32x32x16_bf16(kf[kc], qf[kc], s, 0, 0, 0);

    bf16x8 vf[8];
#pragma unroll
    for (int w2 = 0; w2 < 2; ++w2)
#pragma unroll
      for (int dt = 0; dt < 4; ++dt)
        vf[w2*4 + dt] = *(const bf16x8*)(vbase + dt*65536 + (it*2 + w2)*512);

    float e[16];
#pragma unroll
    for (int r = 0; r < 16; ++r) e[r] = __builtin_amdgcn_exp2f(s[r] * SCALE_L2E);
    float ps = 0.f;
#pragma unroll
    for (int r = 0; r < 16; ++r) ps += e[r];
    rs += ps;

    bf16x8 pf[2];
#pragma unroll
    for (int w2 = 0; w2 < 2; ++w2) {
      unsigned a0, a1, b0, b1;
      asm("v_cvt_pk_bf16_f32 %0, %1, %2" : "=v"(a0) : "v"(e[8*w2+0]), "v"(e[8*w2+1]));
      asm("v_cvt_pk_bf16_f32 %0, %1, %2" : "=v"(a1) : "v"(e[8*w2+2]), "v"(e[8*w2+3]));
      asm("v_cvt_pk_bf16_f32 %0, %1, %2" : "=v"(b0) : "v"(e[8*w2+4]), "v"(e[8*w2+5]));
      asm("v_cvt_pk_bf16_f32 %0, %1, %2" : "=v"(b1) : "v"(e[8*w2+6]), "v"(e[8*w2+7]));
      asm("v_permlane32_swap_b32 %0, %1" : "+v"(a0), "+v"(b0));
      asm("v_permlane32_swap_b32 %0, %1" : "+v"(a1), "+v"(b1));
      u32x4 pw = {a0, a1, b0, b1};
      pf[w2] = __builtin_bit_cast(bf16x8, pw);
    }

#pragma unroll
    for (int dt = 0; dt < 4; ++dt) {
      oacc[dt] = __builtin_amdgcn_mfma_f32_32x32x16_bf16(vf[dt],     pf[0], oacc[dt], 0, 0, 0);
      oacc[dt] = __builtin_amdgcn_mfma_f32_32x32x16_bf16(vf[4 + dt], pf[1], oacc[dt], 0, 0, 0);
    }
  }

  // ---- epilogue: rowsum merge, then 4-phase O reduction over the 2 m-halves ----
  rs += __shfl_xor(rs, 32, 64);
  if (lane < 32) rsred[wave][lm] = rs;
  __syncthreads();
  if (t < 128) {
    const int tlg = t >> 5, tl = t & 31;
    const float tot = rsred[tlg][tl] + rsred[4 + tlg][tl];
    rsw[(size_t)bh*2048 + lt*128 + t] = tot;
    invb[t] = 1.0f / tot;
  }

#pragma unroll
  for (int dt = 0; dt < 4; ++dt) {
    __syncthreads();
#pragma unroll
    for (int c = 0; c < 4; ++c) {
      float4 v4 = { oacc[dt][4*c + 0], oacc[dt][4*c + 1], oacc[dt][4*c + 2], oacc[dt][4*c + 3] };
      *(float4*)&slab[wave][lm][8*c + 4*hi] = v4;
    }
    __syncthreads();
    const int tlg = t >> 7, idx = t & 127;
    const int l = idx >> 2, d0 = (idx & 3) * 8;
    const float iv = invb[tlg*32 + l];
    float4 x0 = *(const float4*)&slab[tlg][l][d0];
    float4 x1 = *(const float4*)&slab[tlg][l][d0 + 4];
    float4 y0 = *(const float4*)&slab[4 + tlg][l][d0];
    float4 y1 = *(const float4*)&slab[4 + tlg][l][d0 + 4];
    float4 o0 = { (x0.x + y0.x)*iv, (x0.y + y0.y)*iv, (x0.z + y0.z)*iv, (x0.w + y0.w)*iv };
    float4 o1 = { (x1.x + y1.x)*iv, (x1.y + y1.y)*iv, (x1.z + y1.z)*iv, (x1.w + y1.w)*iv };
    float* op = outp + ((size_t)(b*2048 + lt*128 + tlg*32 + l))*1024 + h*128 + dt*32 + d0;
    *(float4*)op = o0;
    *(float4*)(op + 4) = o1;
  }
}

// ---------------- K4: head-mean attention weights (LDS-staged GEMM version) ----------------
__global__ __launch_bounds__(256) void k_attn_mean(
    const unsigned short* __restrict__ qw, const unsigned short* __restrict__ kb,
    const float* __restrict__ rsw, float* __restrict__ meanp) {
  __shared__ unsigned short Qs[128*128];   // 32 KB
  __shared__ unsigned short Ks[128*128];   // 32 KB
  __shared__ float inv_s[8*128];           // 4 KB
  const int mt = blockIdx.x;   // 0..15
  const int lt = blockIdx.y;   // 0..15
  const int b  = blockIdx.z;   // 0..1
  const int t = threadIdx.x;
  const int wave = t >> 6, lane = t & 63;
  const int lrow = lane & 15, grp = lane >> 4;
  const int wl = wave >> 1, wm = wave & 1;
  const int trow = t >> 4;     // 0..15 (staging row-within-16)
  const int tcol = t & 15;     // staging 16B-granule column

  for (int idx = t; idx < 1024; idx += 256) {
    int hh = idx >> 7, ll = idx & 127;
    inv_s[idx] = 1.0f / rsw[(size_t)(b*8 + hh)*2048 + lt*128 + ll];
  }

  f32x4 acc[4][4] = {};

  for (int h = 0; h < 8; ++h) {
    __syncthreads();
    const unsigned short* qbase = qw + ((size_t)(b*2048 + lt*128) * 1024 + h*128);
    const unsigned short* kbase = kb + ((size_t)(b*2048 + mt*128) * 1024 + h*128);
#pragma unroll
    for (int i = 0; i < 8; ++i) {
      const int row = i*16 + trow;
      const int sc = (tcol ^ (row & 7)) * 8;
      gl_lds16(qbase + (size_t)row*1024 + sc, &Qs[i*2048 + t*8]);
      gl_lds16(kbase + (size_t)row*1024 + sc, &Ks[i*2048 + t*8]);
    }
    __syncthreads();

    f32x4 s[4][4] = {};
#pragma unroll
    for (int ks = 0; ks < 4; ++ks) {
      bf16x8 af[4], bf[4];
#pragma unroll
      for (int lf = 0; lf < 4; ++lf) {
        const int row = wl*64 + lf*16 + lrow;
        af[lf] = *(const bf16x8*)&Qs[row*128 + ((ks*32 + grp*8) ^ ((row & 7) << 3))];
      }
#pragma unroll
      for (int mf = 0; mf < 4; ++mf) {
        const int row = wm*64 + mf*16 + lrow;
        bf[mf] = *(const bf16x8*)&Ks[row*128 + ((ks*32 + grp*8) ^ ((row & 7) << 3))];
      }
#pragma unroll
      for (int lf = 0; lf < 4; ++lf)
#pragma unroll
        for (int mf = 0; mf < 4; ++mf)
          s[lf][mf] = __builtin_amdgcn_mfma_f32_16x16x32_bf16(af[lf], bf[mf], s[lf][mf], 0, 0, 0);
    }
#pragma unroll
    for (int lf = 0; lf < 4; ++lf)
#pragma unroll
      for (int i = 0; i < 4; ++i) {
        const float iv = inv_s[h*128 + wl*64 + lf*16 + grp*4 + i];
#pragma unroll
        for (int mf = 0; mf < 4; ++mf)
          acc[lf][mf][i] += __builtin_amdgcn_exp2f(s[lf][mf][i] * SCALE_L2E) * iv;
      }
  }

#pragma unroll
  for (int lf = 0; lf < 4; ++lf)
#pragma unroll
    for (int i = 0; i < 4; ++i) {
      const int l = lt*128 + wl*64 + lf*16 + grp*4 + i;
      const size_t rowo = (size_t)(b*2048 + l) * 2048;
#pragma unroll
      for (int mf = 0; mf < 4; ++mf)
        meanp[rowo + mt*128 + wm*64 + mf*16 + lrow] = acc[lf][mf][i] * 0.125f;
    }
}

extern "C" void kernel_launch(void* const* d_in, const int* in_sizes, int n_in,
                              void* d_out, int out_size, void* d_ws, size_t ws_size,
                              hipStream_t stream) {
  (void)in_sizes; (void)n_in; (void)out_size; (void)ws_size;
  const float* query = (const float*)d_in[0];
  const float* Wq = (const float*)d_in[1];
  const float* bq = (const float*)d_in[2];
  const float* Wk = (const float*)d_in[3];
  const float* bk = (const float*)d_in[4];
  const float* Wv = (const float*)d_in[5];
  const float* bv = (const float*)d_in[6];
  float* outp  = (float*)d_out;
  float* meanp = outp + 4194304;           // (B,L,DM) then (B,L,L)

  char* ws = (char*)d_ws;
  unsigned short* xb    = (unsigned short*)(ws);              // 8.4 MB
  unsigned short* wb    = (unsigned short*)(ws + 8388608);    // 6.3 MB (Wq,Wk,Wv)
  unsigned short* qws   = (unsigned short*)(ws + 14680064);   // 8.4 MB (sign-twisted q, row-major)
  unsigned short* kws   = (unsigned short*)(ws + 23068672);   // 8.4 MB (k row-major, for mean)
  unsigned short* kfrag = (unsigned short*)(ws + 31457280);   // 8.4 MB (k frag-order)
  unsigned short* vfrag = (unsigned short*)(ws + 39845888);   // 8.4 MB (v frag-order)
  float*          rsw   = (float*)(ws + 48234496);            // 128 KB rowsums

  k_convert<<<3584, 256, 0, stream>>>(query, Wq, Wk, Wv, xb, wb);
  k_proj<<<dim3(8, 32, 3), 256, 0, stream>>>(xb, wb, bq, bk, bv, qws, kws, vfrag);
  k_repack<<<2048, 256, 0, stream>>>(kws, kfrag);
  k_attn_out<<<256, 512, 0, stream>>>(qws, kfrag, vfrag, outp, rsw);
  k_attn_mean<<<dim3(16, 16, 2), 256, 0, stream>>>(qws, kws, rsw, meanp);
}

// Round 8
// 187.654 us; speedup vs baseline: 1.0009x; 1.0009x over previous
//
#include <hip/hip_runtime.h>

typedef __attribute__((ext_vector_type(8))) __bf16 bf16x8;
typedef __attribute__((ext_vector_type(4))) __bf16 bf16x4;
typedef __attribute__((ext_vector_type(4))) float f32x4;
typedef __attribute__((ext_vector_type(16))) float f32x16;
typedef __attribute__((ext_vector_type(8))) unsigned short us8;
typedef __attribute__((ext_vector_type(4))) unsigned int u32x4;

constexpr float SCALE_L2E = 0.08838834764831845f * 1.4426950408889634f; // (1/sqrt(128))*log2(e)

__device__ __forceinline__ unsigned short f2bf(float f) {
  unsigned int u = __float_as_uint(f);
  u = (u + 0x7FFFu + ((u >> 16) & 1u)) >> 16;
  return (unsigned short)u;
}

__device__ __forceinline__ void gl_lds16(const void* g, void* l) {
  __builtin_amdgcn_global_load_lds(
      (__attribute__((address_space(1))) void*)const_cast<void*>(g),
      (__attribute__((address_space(3))) void*)l, 16, 0, 0);
}

// ---------------- K0: f32 -> bf16 convert (query + 3 weight matrices) ----------------
__global__ __launch_bounds__(256) void k_convert(
    const float* __restrict__ q, const float* __restrict__ wq,
    const float* __restrict__ wk, const float* __restrict__ wv,
    unsigned short* __restrict__ xb, unsigned short* __restrict__ wb) {
  long i = ((long)blockIdx.x * 256 + threadIdx.x) * 8;
  const float* s; unsigned short* d;
  if (i < 4194304)      { s = q  + i;             d = xb + i; }
  else if (i < 5242880) { s = wq + (i - 4194304); d = wb + (i - 4194304); }
  else if (i < 6291456) { s = wk + (i - 5242880); d = wb + 1048576 + (i - 5242880); }
  else                  { s = wv + (i - 6291456); d = wb + 2097152 + (i - 6291456); }
  float4 a = *(const float4*)s;
  float4 b = *(const float4*)(s + 4);
  us8 r;
  r[0]=f2bf(a.x); r[1]=f2bf(a.y); r[2]=f2bf(a.z); r[3]=f2bf(a.w);
  r[4]=f2bf(b.x); r[5]=f2bf(b.y); r[6]=f2bf(b.z); r[7]=f2bf(b.w);
  *(us8*)d = r;
}

// ---------------- K1: projection GEMM  C = X @ W^T + b  (z selects q/k/v) ----------------
// z==0 (q): sign twist, row-major out. z==1 (k): row-major out (repacked later).
// z==2 (v): written DIRECTLY in PV A-fragment order:
//   vfrag[bh][dt][mc][lane][j]  where lane=(d&31)+32*((m>>3)&1), j=m&7, dt=d>>5, mc=m>>4.
__global__ __launch_bounds__(256) void k_proj(
    const unsigned short* __restrict__ xb, const unsigned short* __restrict__ wb,
    const float* __restrict__ bq, const float* __restrict__ bk, const float* __restrict__ bv,
    unsigned short* __restrict__ oq, unsigned short* __restrict__ ok_, unsigned short* __restrict__ vt) {
  __shared__ unsigned short As[4096]; // 128 rows x 32 k
  __shared__ unsigned short Bs[4096];
  const int t = threadIdx.x;
  const int wave = t >> 6, lane = t & 63;
  const int lrow = lane & 15, grp = lane >> 4;
  const int z = blockIdx.z;
  const unsigned short* w = wb + (size_t)z * 1048576;
  const float* bias = (z == 0) ? bq : ((z == 1) ? bk : bv);

  const unsigned short* asrc = xb + ((size_t)(blockIdx.y * 128 + (t >> 2)) * 1024 + (t & 3) * 8);
  const unsigned short* bsrc = w  + ((size_t)(blockIdx.x * 128 + (t >> 2)) * 1024 + (t & 3) * 8);

  f32x4 acc[4][4] = {};
  for (int kt = 0; kt < 32; ++kt) {
    gl_lds16(asrc + kt*32,              &As[t*8]);
    gl_lds16(asrc + kt*32 + 64*1024,    &As[2048 + t*8]);
    gl_lds16(bsrc + kt*32,              &Bs[t*8]);
    gl_lds16(bsrc + kt*32 + 64*1024,    &Bs[2048 + t*8]);
    __syncthreads();
    const int wr = wave >> 1, wc = wave & 1;
    bf16x8 af[4], bf[4];
#pragma unroll
    for (int mf = 0; mf < 4; ++mf)
      af[mf] = *(const bf16x8*)&As[(wr*64 + mf*16 + lrow)*32 + grp*8];
#pragma unroll
    for (int nf = 0; nf < 4; ++nf)
      bf[nf] = *(const bf16x8*)&Bs[(wc*64 + nf*16 + lrow)*32 + grp*8];
#pragma unroll
    for (int mf = 0; mf < 4; ++mf)
#pragma unroll
      for (int nf = 0; nf < 4; ++nf)
        acc[mf][nf] = __builtin_amdgcn_mfma_f32_16x16x32_bf16(af[mf], bf[nf], acc[mf][nf], 0, 0, 0);
    __syncthreads();
  }
  const int wr = wave >> 1, wc = wave & 1;
  if (z == 2) {
#pragma unroll
    for (int nf = 0; nf < 4; ++nf) {
      const int col = blockIdx.x*128 + wc*64 + nf*16 + lrow;   // global channel (h,d)
      const int h = col >> 7, dd = col & 127;
      const int dt = dd >> 5, lv = dd & 31;
      const float bsv = bias[col];
#pragma unroll
      for (int mf = 0; mf < 4; ++mf) {
        const int r0 = blockIdx.y*128 + wr*64 + mf*16 + grp*4;
        const int bb = r0 >> 11, m = r0 & 2047;
        const int mc = m >> 4, him = (m >> 3) & 1, j0 = m & 7;
        bf16x4 pv;
#pragma unroll
        for (int i = 0; i < 4; ++i) pv[i] = (__bf16)(acc[mf][nf][i] + bsv);
        const size_t off = ((((size_t)((bb*8 + h)*4 + dt))*128 + mc)*64 + lv + 32*him)*8 + j0;
        *(bf16x4*)&vt[off] = pv;
      }
    }
  } else {
    unsigned short* dst = (z == 0) ? oq : ok_;
    const float sign = (z == 0 && (lane & 7) >= 4) ? -1.0f : 1.0f;
#pragma unroll
    for (int nf = 0; nf < 4; ++nf) {
      const int col = blockIdx.x*128 + wc*64 + nf*16 + lrow;
      const float bsv = bias[col];
#pragma unroll
      for (int mf = 0; mf < 4; ++mf)
#pragma unroll
        for (int i = 0; i < 4; ++i) {
          const int row = blockIdx.y*128 + wr*64 + mf*16 + grp*4 + i;
          dst[(size_t)row*1024 + col] = f2bf((acc[mf][nf][i] + bsv) * sign);
        }
    }
  }
}

// ---------------- K2: repack K row-major -> QK A-fragment order ----------------
// kfrag[bh][mtile][kc][lane][j]: lane=(m&31)+32*((k>>3)&1), j=k&7, mtile=m>>5, kc=k>>4.
__global__ __launch_bounds__(256) void k_repack(const unsigned short* __restrict__ kws,
                                                unsigned short* __restrict__ kfrag) {
  const int c = blockIdx.x * 256 + threadIdx.x;   // 0..524287 (us8 chunks)
  const int lane = c & 63, kc = (c >> 6) & 7, mtile = (c >> 9) & 63, bh = c >> 15;
  const int b = bh >> 3, h = bh & 7;
  const int m = mtile*32 + (lane & 31);
  const int kd = kc*16 + (lane >> 5)*8;
  us8 v = *(const us8*)&kws[((size_t)(b*2048 + m))*1024 + h*128 + kd];
  *(us8*)&kfrag[(size_t)c * 8] = v;
}

// ---------------- K3: fused attention out + rowsum (barrier-free main loop) ----------------
// Identical loop body to round 6 (verified correct); ONLY change: __launch_bounds__(512,2)
// so the allocator gets the 256-VGPR budget the ~210-register live set needs
// (round-6's 84-VGPR build thrashed: MfmaUtil 13%, everything idle).
__global__ __launch_bounds__(512, 2) void k_attn_out(
    const unsigned short* __restrict__ qw, const unsigned short* __restrict__ kfrag,
    const unsigned short* __restrict__ vfrag, float* __restrict__ outp,
    float* __restrict__ rsw) {
  __shared__ float slab[8][32][36];   // 36 KB, padded
  __shared__ float rsred[8][32];
  __shared__ float invb[128];

  const int bid = blockIdx.x;
  const int xcd = bid & 7, r_ = bid >> 3;
  const int bh = (xcd << 1) | (r_ & 1);    // 2 bh per XCD -> K/V L2-resident
  const int lt = r_ >> 1;                  // 0..15 (128-l tile)
  const int b = bh >> 3, h = bh & 7;
  const int t = threadIdx.x;
  const int wave = t >> 6, lane = t & 63;
  const int mg = wave >> 2, lg = wave & 3;
  const int lm = lane & 31, hi = lane >> 5;

  // Q fragments (B-operand: col = lane&31 = l, k = kc*16 + 8*hi + j). Loaded once.
  bf16x8 qf[8];
  {
    const unsigned short* qp = qw + ((size_t)(b*2048 + lt*128 + lg*32 + lm))*1024
                                  + (size_t)h*128 + hi*8;
#pragma unroll
    for (int kc = 0; kc < 8; ++kc) qf[kc] = *(const bf16x8*)(qp + kc*16);
  }

  const unsigned short* kbase = kfrag + (size_t)bh*262144 + (size_t)mg*32*4096 + lane*8;
  const unsigned short* vbase = vfrag + (size_t)bh*262144 + (size_t)mg*64*512  + lane*8;

  f32x16 oacc[4] = {};
  float rs = 0.f;

#pragma unroll 2
  for (int it = 0; it < 32; ++it) {
    bf16x8 kf[8];
#pragma unroll
    for (int kc = 0; kc < 8; ++kc)
      kf[kc] = *(const bf16x8*)(kbase + it*4096 + kc*512);
    f32x16 s = {};
#pragma unroll
    for (int kc = 0; kc < 8; ++kc)
      s = __builtin_amdgcn_mfma_f32_32x32x16_bf16(kf[kc], qf[kc], s, 0, 0, 0);

    bf16x8 vf[8];
#pragma unroll
    for (int w2 = 0; w2 < 2; ++w2)
#pragma unroll
      for (int dt = 0; dt < 4; ++dt)
        vf[w2*4 + dt] = *(const bf16x8*)(vbase + dt*65536 + (it*2 + w2)*512);

    float e[16];
#pragma unroll
    for (int r = 0; r < 16; ++r) e[r] = __builtin_amdgcn_exp2f(s[r] * SCALE_L2E);
    float ps = 0.f;
#pragma unroll
    for (int r = 0; r < 16; ++r) ps += e[r];
    rs += ps;

    bf16x8 pf[2];
#pragma unroll
    for (int w2 = 0; w2 < 2; ++w2) {
      unsigned a0, a1, b0, b1;
      asm("v_cvt_pk_bf16_f32 %0, %1, %2" : "=v"(a0) : "v"(e[8*w2+0]), "v"(e[8*w2+1]));
      asm("v_cvt_pk_bf16_f32 %0, %1, %2" : "=v"(a1) : "v"(e[8*w2+2]), "v"(e[8*w2+3]));
      asm("v_cvt_pk_bf16_f32 %0, %1, %2" : "=v"(b0) : "v"(e[8*w2+4]), "v"(e[8*w2+5]));
      asm("v_cvt_pk_bf16_f32 %0, %1, %2" : "=v"(b1) : "v"(e[8*w2+6]), "v"(e[8*w2+7]));
      asm("v_permlane32_swap_b32 %0, %1" : "+v"(a0), "+v"(b0));
      asm("v_permlane32_swap_b32 %0, %1" : "+v"(a1), "+v"(b1));
      u32x4 pw = {a0, a1, b0, b1};
      pf[w2] = __builtin_bit_cast(bf16x8, pw);
    }

#pragma unroll
    for (int dt = 0; dt < 4; ++dt) {
      oacc[dt] = __builtin_amdgcn_mfma_f32_32x32x16_bf16(vf[dt],     pf[0], oacc[dt], 0, 0, 0);
      oacc[dt] = __builtin_amdgcn_mfma_f32_32x32x16_bf16(vf[4 + dt], pf[1], oacc[dt], 0, 0, 0);
    }
  }

  // ---- epilogue: rowsum merge, then 4-phase O reduction over the 2 m-halves ----
  rs += __shfl_xor(rs, 32, 64);
  if (lane < 32) rsred[wave][lm] = rs;
  __syncthreads();
  if (t < 128) {
    const int tlg = t >> 5, tl = t & 31;
    const float tot = rsred[tlg][tl] + rsred[4 + tlg][tl];
    rsw[(size_t)bh*2048 + lt*128 + t] = tot;
    invb[t] = 1.0f / tot;
  }

#pragma unroll
  for (int dt = 0; dt < 4; ++dt) {
    __syncthreads();
#pragma unroll
    for (int c = 0; c < 4; ++c) {
      float4 v4 = { oacc[dt][4*c + 0], oacc[dt][4*c + 1], oacc[dt][4*c + 2], oacc[dt][4*c + 3] };
      *(float4*)&slab[wave][lm][8*c + 4*hi] = v4;
    }
    __syncthreads();
    const int tlg = t >> 7, idx = t & 127;
    const int l = idx >> 2, d0 = (idx & 3) * 8;
    const float iv = invb[tlg*32 + l];
    float4 x0 = *(const float4*)&slab[tlg][l][d0];
    float4 x1 = *(const float4*)&slab[tlg][l][d0 + 4];
    float4 y0 = *(const float4*)&slab[4 + tlg][l][d0];
    float4 y1 = *(const float4*)&slab[4 + tlg][l][d0 + 4];
    float4 o0 = { (x0.x + y0.x)*iv, (x0.y + y0.y)*iv, (x0.z + y0.z)*iv, (x0.w + y0.w)*iv };
    float4 o1 = { (x1.x + y1.x)*iv, (x1.y + y1.y)*iv, (x1.z + y1.z)*iv, (x1.w + y1.w)*iv };
    float* op = outp + ((size_t)(b*2048 + lt*128 + tlg*32 + l))*1024 + h*128 + dt*32 + d0;
    *(float4*)op = o0;
    *(float4*)(op + 4) = o1;
  }
}

// ---------------- K4: head-mean attention weights (LDS-staged GEMM version) ----------------
__global__ __launch_bounds__(256) void k_attn_mean(
    const unsigned short* __restrict__ qw, const unsigned short* __restrict__ kb,
    const float* __restrict__ rsw, float* __restrict__ meanp) {
  __shared__ unsigned short Qs[128*128];   // 32 KB
  __shared__ unsigned short Ks[128*128];   // 32 KB
  __shared__ float inv_s[8*128];           // 4 KB
  const int mt = blockIdx.x;   // 0..15
  const int lt = blockIdx.y;   // 0..15
  const int b  = blockIdx.z;   // 0..1
  const int t = threadIdx.x;
  const int wave = t >> 6, lane = t & 63;
  const int lrow = lane & 15, grp = lane >> 4;
  const int wl = wave >> 1, wm = wave & 1;
  const int trow = t >> 4;     // 0..15 (staging row-within-16)
  const int tcol = t & 15;     // staging 16B-granule column

  for (int idx = t; idx < 1024; idx += 256) {
    int hh = idx >> 7, ll = idx & 127;
    inv_s[idx] = 1.0f / rsw[(size_t)(b*8 + hh)*2048 + lt*128 + ll];
  }

  f32x4 acc[4][4] = {};

  for (int h = 0; h < 8; ++h) {
    __syncthreads();
    const unsigned short* qbase = qw + ((size_t)(b*2048 + lt*128) * 1024 + h*128);
    const unsigned short* kbase = kb + ((size_t)(b*2048 + mt*128) * 1024 + h*128);
#pragma unroll
    for (int i = 0; i < 8; ++i) {
      const int row = i*16 + trow;
      const int sc = (tcol ^ (row & 7)) * 8;
      gl_lds16(qbase + (size_t)row*1024 + sc, &Qs[i*2048 + t*8]);
      gl_lds16(kbase + (size_t)row*1024 + sc, &Ks[i*2048 + t*8]);
    }
    __syncthreads();

    f32x4 s[4][4] = {};
#pragma unroll
    for (int ks = 0; ks < 4; ++ks) {
      bf16x8 af[4], bf[4];
#pragma unroll
      for (int lf = 0; lf < 4; ++lf) {
        const int row = wl*64 + lf*16 + lrow;
        af[lf] = *(const bf16x8*)&Qs[row*128 + ((ks*32 + grp*8) ^ ((row & 7) << 3))];
      }
#pragma unroll
      for (int mf = 0; mf < 4; ++mf) {
        const int row = wm*64 + mf*16 + lrow;
        bf[mf] = *(const bf16x8*)&Ks[row*128 + ((ks*32 + grp*8) ^ ((row & 7) << 3))];
      }
#pragma unroll
      for (int lf = 0; lf < 4; ++lf)
#pragma unroll
        for (int mf = 0; mf < 4; ++mf)
          s[lf][mf] = __builtin_amdgcn_mfma_f32_16x16x32_bf16(af[lf], bf[mf], s[lf][mf], 0, 0, 0);
    }
#pragma unroll
    for (int lf = 0; lf < 4; ++lf)
#pragma unroll
      for (int i = 0; i < 4; ++i) {
        const float iv = inv_s[h*128 + wl*64 + lf*16 + grp*4 + i];
#pragma unroll
        for (int mf = 0; mf < 4; ++mf)
          acc[lf][mf][i] += __builtin_amdgcn_exp2f(s[lf][mf][i] * SCALE_L2E) * iv;
      }
  }

#pragma unroll
  for (int lf = 0; lf < 4; ++lf)
#pragma unroll
    for (int i = 0; i < 4; ++i) {
      const int l = lt*128 + wl*64 + lf*16 + grp*4 + i;
      const size_t rowo = (size_t)(b*2048 + l) * 2048;
#pragma unroll
      for (int mf = 0; mf < 4; ++mf)
        meanp[rowo + mt*128 + wm*64 + mf*16 + lrow] = acc[lf][mf][i] * 0.125f;
    }
}

extern "C" void kernel_launch(void* const* d_in, const int* in_sizes, int n_in,
                              void* d_out, int out_size, void* d_ws, size_t ws_size,
                              hipStream_t stream) {
  (void)in_sizes; (void)n_in; (void)out_size; (void)ws_size;
  const float* query = (const float*)d_in[0];
  const float* Wq = (const float*)d_in[1];
  const float* bq = (const float*)d_in[2];
  const float* Wk = (const float*)d_in[3];
  const float* bk = (const float*)d_in[4];
  const float* Wv = (const float*)d_in[5];
  const float* bv = (const float*)d_in[6];
  float* outp  = (float*)d_out;
  float* meanp = outp + 4194304;           // (B,L,DM) then (B,L,L)

  char* ws = (char*)d_ws;
  unsigned short* xb    = (unsigned short*)(ws);              // 8.4 MB
  unsigned short* wb    = (unsigned short*)(ws + 8388608);    // 6.3 MB (Wq,Wk,Wv)
  unsigned short* qws   = (unsigned short*)(ws + 14680064);   // 8.4 MB (sign-twisted q, row-major)
  unsigned short* kws   = (unsigned short*)(ws + 23068672);   // 8.4 MB (k row-major, for mean)
  unsigned short* kfrag = (unsigned short*)(ws + 31457280);   // 8.4 MB (k frag-order)
  unsigned short* vfrag = (unsigned short*)(ws + 39845888);   // 8.4 MB (v frag-order)
  float*          rsw   = (float*)(ws + 48234496);            // 128 KB rowsums

  k_convert<<<3584, 256, 0, stream>>>(query, Wq, Wk, Wv, xb, wb);
  k_proj<<<dim3(8, 32, 3), 256, 0, stream>>>(xb, wb, bq, bk, bv, qws, kws, vfrag);
  k_repack<<<2048, 256, 0, stream>>>(kws, kfrag);
  k_attn_out<<<256, 512, 0, stream>>>(qws, kfrag, vfrag, outp, rsw);
  k_attn_mean<<<dim3(16, 16, 2), 256, 0, stream>>>(qws, kws, rsw, meanp);
}

// Round 9
// 138.133 us; speedup vs baseline: 1.3597x; 1.3585x over previous
//
#include <hip/hip_runtime.h>

typedef __attribute__((ext_vector_type(8))) __bf16 bf16x8;
typedef __attribute__((ext_vector_type(4))) __bf16 bf16x4;
typedef __attribute__((ext_vector_type(4))) float f32x4;
typedef __attribute__((ext_vector_type(16))) float f32x16;
typedef __attribute__((ext_vector_type(8))) unsigned short us8;
typedef __attribute__((ext_vector_type(4))) unsigned int u32x4;

constexpr float SCALE_L2E = 0.08838834764831845f * 1.4426950408889634f; // (1/sqrt(128))*log2(e)

__device__ __forceinline__ unsigned short f2bf(float f) {
  unsigned int u = __float_as_uint(f);
  u = (u + 0x7FFFu + ((u >> 16) & 1u)) >> 16;
  return (unsigned short)u;
}

__device__ __forceinline__ void gl_lds16(const void* g, void* l) {
  __builtin_amdgcn_global_load_lds(
      (__attribute__((address_space(1))) void*)const_cast<void*>(g),
      (__attribute__((address_space(3))) void*)l, 16, 0, 0);
}

// ---------------- K0: f32 -> bf16 convert (query + 3 weight matrices) ----------------
__global__ __launch_bounds__(256) void k_convert(
    const float* __restrict__ q, const float* __restrict__ wq,
    const float* __restrict__ wk, const float* __restrict__ wv,
    unsigned short* __restrict__ xb, unsigned short* __restrict__ wb) {
  long i = ((long)blockIdx.x * 256 + threadIdx.x) * 8;
  const float* s; unsigned short* d;
  if (i < 4194304)      { s = q  + i;             d = xb + i; }
  else if (i < 5242880) { s = wq + (i - 4194304); d = wb + (i - 4194304); }
  else if (i < 6291456) { s = wk + (i - 5242880); d = wb + 1048576 + (i - 5242880); }
  else                  { s = wv + (i - 6291456); d = wb + 2097152 + (i - 6291456); }
  float4 a = *(const float4*)s;
  float4 b = *(const float4*)(s + 4);
  us8 r;
  r[0]=f2bf(a.x); r[1]=f2bf(a.y); r[2]=f2bf(a.z); r[3]=f2bf(a.w);
  r[4]=f2bf(b.x); r[5]=f2bf(b.y); r[6]=f2bf(b.z); r[7]=f2bf(b.w);
  *(us8*)d = r;
}

// ---------------- K1: projection GEMM  C = X @ W^T + b  (z selects q/k/v) ----------------
// z==0 (q): sign twist, row-major out. z==1 (k): row-major out (repacked later).
// z==2 (v): written DIRECTLY in PV A-fragment order:
//   vfrag[bh][dt][mc][lane][j]  where lane=(d&31)+32*((m>>3)&1), j=m&7, dt=d>>5, mc=m>>4.
__global__ __launch_bounds__(256) void k_proj(
    const unsigned short* __restrict__ xb, const unsigned short* __restrict__ wb,
    const float* __restrict__ bq, const float* __restrict__ bk, const float* __restrict__ bv,
    unsigned short* __restrict__ oq, unsigned short* __restrict__ ok_, unsigned short* __restrict__ vt) {
  __shared__ unsigned short As[4096]; // 128 rows x 32 k
  __shared__ unsigned short Bs[4096];
  const int t = threadIdx.x;
  const int wave = t >> 6, lane = t & 63;
  const int lrow = lane & 15, grp = lane >> 4;
  const int z = blockIdx.z;
  const unsigned short* w = wb + (size_t)z * 1048576;
  const float* bias = (z == 0) ? bq : ((z == 1) ? bk : bv);

  const unsigned short* asrc = xb + ((size_t)(blockIdx.y * 128 + (t >> 2)) * 1024 + (t & 3) * 8);
  const unsigned short* bsrc = w  + ((size_t)(blockIdx.x * 128 + (t >> 2)) * 1024 + (t & 3) * 8);

  f32x4 acc[4][4] = {};
  for (int kt = 0; kt < 32; ++kt) {
    gl_lds16(asrc + kt*32,              &As[t*8]);
    gl_lds16(asrc + kt*32 + 64*1024,    &As[2048 + t*8]);
    gl_lds16(bsrc + kt*32,              &Bs[t*8]);
    gl_lds16(bsrc + kt*32 + 64*1024,    &Bs[2048 + t*8]);
    __syncthreads();
    const int wr = wave >> 1, wc = wave & 1;
    bf16x8 af[4], bf[4];
#pragma unroll
    for (int mf = 0; mf < 4; ++mf)
      af[mf] = *(const bf16x8*)&As[(wr*64 + mf*16 + lrow)*32 + grp*8];
#pragma unroll
    for (int nf = 0; nf < 4; ++nf)
      bf[nf] = *(const bf16x8*)&Bs[(wc*64 + nf*16 + lrow)*32 + grp*8];
#pragma unroll
    for (int mf = 0; mf < 4; ++mf)
#pragma unroll
      for (int nf = 0; nf < 4; ++nf)
        acc[mf][nf] = __builtin_amdgcn_mfma_f32_16x16x32_bf16(af[mf], bf[nf], acc[mf][nf], 0, 0, 0);
    __syncthreads();
  }
  const int wr = wave >> 1, wc = wave & 1;
  if (z == 2) {
#pragma unroll
    for (int nf = 0; nf < 4; ++nf) {
      const int col = blockIdx.x*128 + wc*64 + nf*16 + lrow;   // global channel (h,d)
      const int h = col >> 7, dd = col & 127;
      const int dt = dd >> 5, lv = dd & 31;
      const float bsv = bias[col];
#pragma unroll
      for (int mf = 0; mf < 4; ++mf) {
        const int r0 = blockIdx.y*128 + wr*64 + mf*16 + grp*4;
        const int bb = r0 >> 11, m = r0 & 2047;
        const int mc = m >> 4, him = (m >> 3) & 1, j0 = m & 7;
        bf16x4 pv;
#pragma unroll
        for (int i = 0; i < 4; ++i) pv[i] = (__bf16)(acc[mf][nf][i] + bsv);
        const size_t off = ((((size_t)((bb*8 + h)*4 + dt))*128 + mc)*64 + lv + 32*him)*8 + j0;
        *(bf16x4*)&vt[off] = pv;
      }
    }
  } else {
    unsigned short* dst = (z == 0) ? oq : ok_;
    const float sign = (z == 0 && (lane & 7) >= 4) ? -1.0f : 1.0f;
#pragma unroll
    for (int nf = 0; nf < 4; ++nf) {
      const int col = blockIdx.x*128 + wc*64 + nf*16 + lrow;
      const float bsv = bias[col];
#pragma unroll
      for (int mf = 0; mf < 4; ++mf)
#pragma unroll
        for (int i = 0; i < 4; ++i) {
          const int row = blockIdx.y*128 + wr*64 + mf*16 + grp*4 + i;
          dst[(size_t)row*1024 + col] = f2bf((acc[mf][nf][i] + bsv) * sign);
        }
    }
  }
}

// ---------------- K2: repack K row-major -> QK A-fragment order ----------------
// kfrag[bh][mtile][kc][lane][j]: lane=(m&31)+32*((k>>3)&1), j=k&7, mtile=m>>5, kc=k>>4.
__global__ __launch_bounds__(256) void k_repack(const unsigned short* __restrict__ kws,
                                                unsigned short* __restrict__ kfrag) {
  const int c = blockIdx.x * 256 + threadIdx.x;   // 0..524287 (us8 chunks)
  const int lane = c & 63, kc = (c >> 6) & 7, mtile = (c >> 9) & 63, bh = c >> 15;
  const int b = bh >> 3, h = bh & 7;
  const int m = mtile*32 + (lane & 31);
  const int kd = kc*16 + (lane >> 5)*8;
  us8 v = *(const us8*)&kws[((size_t)(b*2048 + m))*1024 + h*128 + kd];
  *(us8*)&kfrag[(size_t)c * 8] = v;
}

// ---------------- K3: fused attention out + rowsum ----------------
// Round-8 math (verified PASS) with ONE change: K/V routed through double-buffered
// LDS via global_load_lds (no VGPR destinations -> loads batch-issue; the
// global->reg version serialized load/waitcnt pairs at 84 VGPRs, 99us).
// 2-phase pipeline: STAGE(it+1) issued before compute(it); one __syncthreads per
// iteration is the single drain point. Frag-order buffers => LDS linear, all
// gl_lds dests and ds_read_b128 lane-contiguous (2-way aliasing = free).
__global__ __launch_bounds__(512) void k_attn_out(
    const unsigned short* __restrict__ qw, const unsigned short* __restrict__ kfrag,
    const unsigned short* __restrict__ vfrag, float* __restrict__ outp,
    float* __restrict__ rsw) {
  __shared__ unsigned short KsL[2][8192];  // 2 x 16 KB (two 32-m fragment chunks)
  __shared__ unsigned short VsL[2][8192];  // 2 x 16 KB (16 x 1KB chunks)
  __shared__ float slab[8][32][36];        // 36 KB, padded
  __shared__ float rsred[8][32];
  __shared__ float invb[128];

  const int bid = blockIdx.x;
  const int xcd = bid & 7, r_ = bid >> 3;
  const int bh = (xcd << 1) | (r_ & 1);    // 2 bh per XCD -> K/V L2-resident
  const int lt = r_ >> 1;                  // 0..15 (128-l tile)
  const int b = bh >> 3, h = bh & 7;
  const int t = threadIdx.x;
  const int wave = t >> 6, lane = t & 63;
  const int mg = wave >> 2, lg = wave & 3;
  const int lm = lane & 31, hi = lane >> 5;

  // Q fragments (B-operand: col = lane&31 = l, k = kc*16 + 8*hi + j). Loaded once.
  bf16x8 qf[8];
  {
    const unsigned short* qp = qw + ((size_t)(b*2048 + lt*128 + lg*32 + lm))*1024
                                  + (size_t)h*128 + hi*8;
#pragma unroll
    for (int kc = 0; kc < 8; ++kc) qf[kc] = *(const bf16x8*)(qp + kc*16);
  }

  const unsigned short* kbp = kfrag + (size_t)bh*262144;
  const unsigned short* vbp = vfrag + (size_t)bh*262144;

  // staging decomposition (per thread, 4 x 16B per iteration)
  const int vdt = (t >> 6) & 3, vw2 = (t >> 8) & 1, vi8 = (t & 63) * 8;

  auto STAGE = [&](int buf, int it) {
#pragma unroll
    for (int q = 0; q < 2; ++q)
      gl_lds16(kbp + (q*32 + it)*4096 + t*8, &KsL[buf][q*4096 + t*8]);
#pragma unroll
    for (int r = 0; r < 2; ++r)
      gl_lds16(vbp + vdt*65536 + (r*64 + it*2 + vw2)*512 + vi8, &VsL[buf][r*4096 + t*8]);
  };

  f32x16 oacc[4] = {};
  float rs = 0.f;

  STAGE(0, 0);
  __syncthreads();

  for (int it = 0; it < 32; ++it) {
    const int cur = it & 1;
    if (it + 1 < 32) STAGE(cur ^ 1, it + 1);

    bf16x8 kf[8];
#pragma unroll
    for (int kc = 0; kc < 8; ++kc)
      kf[kc] = *(const bf16x8*)&KsL[cur][mg*4096 + kc*512 + lane*8];
    f32x16 s = {};
#pragma unroll
    for (int kc = 0; kc < 8; ++kc)
      s = __builtin_amdgcn_mfma_f32_32x32x16_bf16(kf[kc], qf[kc], s, 0, 0, 0);

    bf16x8 vf[8];
#pragma unroll
    for (int w2 = 0; w2 < 2; ++w2)
#pragma unroll
      for (int dt = 0; dt < 4; ++dt)
        vf[w2*4 + dt] = *(const bf16x8*)&VsL[cur][(mg*8 + w2*4 + dt)*512 + lane*8];

    float e[16];
#pragma unroll
    for (int r = 0; r < 16; ++r) e[r] = __builtin_amdgcn_exp2f(s[r] * SCALE_L2E);
    float ps = 0.f;
#pragma unroll
    for (int r = 0; r < 16; ++r) ps += e[r];
    rs += ps;

    bf16x8 pf[2];
#pragma unroll
    for (int w2 = 0; w2 < 2; ++w2) {
      unsigned a0, a1, b0, b1;
      asm("v_cvt_pk_bf16_f32 %0, %1, %2" : "=v"(a0) : "v"(e[8*w2+0]), "v"(e[8*w2+1]));
      asm("v_cvt_pk_bf16_f32 %0, %1, %2" : "=v"(a1) : "v"(e[8*w2+2]), "v"(e[8*w2+3]));
      asm("v_cvt_pk_bf16_f32 %0, %1, %2" : "=v"(b0) : "v"(e[8*w2+4]), "v"(e[8*w2+5]));
      asm("v_cvt_pk_bf16_f32 %0, %1, %2" : "=v"(b1) : "v"(e[8*w2+6]), "v"(e[8*w2+7]));
      asm("v_permlane32_swap_b32 %0, %1" : "+v"(a0), "+v"(b0));
      asm("v_permlane32_swap_b32 %0, %1" : "+v"(a1), "+v"(b1));
      u32x4 pw = {a0, a1, b0, b1};
      pf[w2] = __builtin_bit_cast(bf16x8, pw);
    }

#pragma unroll
    for (int dt = 0; dt < 4; ++dt) {
      oacc[dt] = __builtin_amdgcn_mfma_f32_32x32x16_bf16(vf[dt],     pf[0], oacc[dt], 0, 0, 0);
      oacc[dt] = __builtin_amdgcn_mfma_f32_32x32x16_bf16(vf[4 + dt], pf[1], oacc[dt], 0, 0, 0);
    }
    __syncthreads();   // next tile landed (vmcnt) + all reads of cur done
  }

  // ---- epilogue: rowsum merge, then 4-phase O reduction over the 2 m-halves ----
  rs += __shfl_xor(rs, 32, 64);
  if (lane < 32) rsred[wave][lm] = rs;
  __syncthreads();
  if (t < 128) {
    const int tlg = t >> 5, tl = t & 31;
    const float tot = rsred[tlg][tl] + rsred[4 + tlg][tl];
    rsw[(size_t)bh*2048 + lt*128 + t] = tot;
    invb[t] = 1.0f / tot;
  }

#pragma unroll
  for (int dt = 0; dt < 4; ++dt) {
    __syncthreads();
#pragma unroll
    for (int c = 0; c < 4; ++c) {
      float4 v4 = { oacc[dt][4*c + 0], oacc[dt][4*c + 1], oacc[dt][4*c + 2], oacc[dt][4*c + 3] };
      *(float4*)&slab[wave][lm][8*c + 4*hi] = v4;
    }
    __syncthreads();
    const int tlg = t >> 7, idx = t & 127;
    const int l = idx >> 2, d0 = (idx & 3) * 8;
    const float iv = invb[tlg*32 + l];
    float4 x0 = *(const float4*)&slab[tlg][l][d0];
    float4 x1 = *(const float4*)&slab[tlg][l][d0 + 4];
    float4 y0 = *(const float4*)&slab[4 + tlg][l][d0];
    float4 y1 = *(const float4*)&slab[4 + tlg][l][d0 + 4];
    float4 o0 = { (x0.x + y0.x)*iv, (x0.y + y0.y)*iv, (x0.z + y0.z)*iv, (x0.w + y0.w)*iv };
    float4 o1 = { (x1.x + y1.x)*iv, (x1.y + y1.y)*iv, (x1.z + y1.z)*iv, (x1.w + y1.w)*iv };
    float* op = outp + ((size_t)(b*2048 + lt*128 + tlg*32 + l))*1024 + h*128 + dt*32 + d0;
    *(float4*)op = o0;
    *(float4*)(op + 4) = o1;
  }
}

// ---------------- K4: head-mean attention weights (LDS-staged GEMM version) ----------------
__global__ __launch_bounds__(256) void k_attn_mean(
    const unsigned short* __restrict__ qw, const unsigned short* __restrict__ kb,
    const float* __restrict__ rsw, float* __restrict__ meanp) {
  __shared__ unsigned short Qs[128*128];   // 32 KB
  __shared__ unsigned short Ks[128*128];   // 32 KB
  __shared__ float inv_s[8*128];           // 4 KB
  const int mt = blockIdx.x;   // 0..15
  const int lt = blockIdx.y;   // 0..15
  const int b  = blockIdx.z;   // 0..1
  const int t = threadIdx.x;
  const int wave = t >> 6, lane = t & 63;
  const int lrow = lane & 15, grp = lane >> 4;
  const int wl = wave >> 1, wm = wave & 1;
  const int trow = t >> 4;     // 0..15 (staging row-within-16)
  const int tcol = t & 15;     // staging 16B-granule column

  for (int idx = t; idx < 1024; idx += 256) {
    int hh = idx >> 7, ll = idx & 127;
    inv_s[idx] = 1.0f / rsw[(size_t)(b*8 + hh)*2048 + lt*128 + ll];
  }

  f32x4 acc[4][4] = {};

  for (int h = 0; h < 8; ++h) {
    __syncthreads();
    const unsigned short* qbase = qw + ((size_t)(b*2048 + lt*128) * 1024 + h*128);
    const unsigned short* kbase = kb + ((size_t)(b*2048 + mt*128) * 1024 + h*128);
#pragma unroll
    for (int i = 0; i < 8; ++i) {
      const int row = i*16 + trow;
      const int sc = (tcol ^ (row & 7)) * 8;
      gl_lds16(qbase + (size_t)row*1024 + sc, &Qs[i*2048 + t*8]);
      gl_lds16(kbase + (size_t)row*1024 + sc, &Ks[i*2048 + t*8]);
    }
    __syncthreads();

    f32x4 s[4][4] = {};
#pragma unroll
    for (int ks = 0; ks < 4; ++ks) {
      bf16x8 af[4], bf[4];
#pragma unroll
      for (int lf = 0; lf < 4; ++lf) {
        const int row = wl*64 + lf*16 + lrow;
        af[lf] = *(const bf16x8*)&Qs[row*128 + ((ks*32 + grp*8) ^ ((row & 7) << 3))];
      }
#pragma unroll
      for (int mf = 0; mf < 4; ++mf) {
        const int row = wm*64 + mf*16 + lrow;
        bf[mf] = *(const bf16x8*)&Ks[row*128 + ((ks*32 + grp*8) ^ ((row & 7) << 3))];
      }
#pragma unroll
      for (int lf = 0; lf < 4; ++lf)
#pragma unroll
        for (int mf = 0; mf < 4; ++mf)
          s[lf][mf] = __builtin_amdgcn_mfma_f32_16x16x32_bf16(af[lf], bf[mf], s[lf][mf], 0, 0, 0);
    }
#pragma unroll
    for (int lf = 0; lf < 4; ++lf)
#pragma unroll
      for (int i = 0; i < 4; ++i) {
        const float iv = inv_s[h*128 + wl*64 + lf*16 + grp*4 + i];
#pragma unroll
        for (int mf = 0; mf < 4; ++mf)
          acc[lf][mf][i] += __builtin_amdgcn_exp2f(s[lf][mf][i] * SCALE_L2E) * iv;
      }
  }

#pragma unroll
  for (int lf = 0; lf < 4; ++lf)
#pragma unroll
    for (int i = 0; i < 4; ++i) {
      const int l = lt*128 + wl*64 + lf*16 + grp*4 + i;
      const size_t rowo = (size_t)(b*2048 + l) * 2048;
#pragma unroll
      for (int mf = 0; mf < 4; ++mf)
        meanp[rowo + mt*128 + wm*64 + mf*16 + lrow] = acc[lf][mf][i] * 0.125f;
    }
}

extern "C" void kernel_launch(void* const* d_in, const int* in_sizes, int n_in,
                              void* d_out, int out_size, void* d_ws, size_t ws_size,
                              hipStream_t stream) {
  (void)in_sizes; (void)n_in; (void)out_size; (void)ws_size;
  const float* query = (const float*)d_in[0];
  const float* Wq = (const float*)d_in[1];
  const float* bq = (const float*)d_in[2];
  const float* Wk = (const float*)d_in[3];
  const float* bk = (const float*)d_in[4];
  const float* Wv = (const float*)d_in[5];
  const float* bv = (const float*)d_in[6];
  float* outp  = (float*)d_out;
  float* meanp = outp + 4194304;           // (B,L,DM) then (B,L,L)

  char* ws = (char*)d_ws;
  unsigned short* xb    = (unsigned short*)(ws);              // 8.4 MB
  unsigned short* wb    = (unsigned short*)(ws + 8388608);    // 6.3 MB (Wq,Wk,Wv)
  unsigned short* qws   = (unsigned short*)(ws + 14680064);   // 8.4 MB (sign-twisted q, row-major)
  unsigned short* kws   = (unsigned short*)(ws + 23068672);   // 8.4 MB (k row-major, for mean)
  unsigned short* kfrag = (unsigned short*)(ws + 31457280);   // 8.4 MB (k frag-order)
  unsigned short* vfrag = (unsigned short*)(ws + 39845888);   // 8.4 MB (v frag-order)
  float*          rsw   = (float*)(ws + 48234496);            // 128 KB rowsums

  k_convert<<<3584, 256, 0, stream>>>(query, Wq, Wk, Wv, xb, wb);
  k_proj<<<dim3(8, 32, 3), 256, 0, stream>>>(xb, wb, bq, bk, bv, qws, kws, vfrag);
  k_repack<<<2048, 256, 0, stream>>>(kws, kfrag);
  k_attn_out<<<256, 512, 0, stream>>>(qws, kfrag, vfrag, outp, rsw);
  k_attn_mean<<<dim3(16, 16, 2), 256, 0, stream>>>(qws, kws, rsw, meanp);
}

// Round 10
// 136.654 us; speedup vs baseline: 1.3744x; 1.0108x over previous
//
#include <hip/hip_runtime.h>

typedef __attribute__((ext_vector_type(8))) __bf16 bf16x8;
typedef __attribute__((ext_vector_type(4))) __bf16 bf16x4;
typedef __attribute__((ext_vector_type(4))) float f32x4;
typedef __attribute__((ext_vector_type(16))) float f32x16;
typedef __attribute__((ext_vector_type(8))) unsigned short us8;
typedef __attribute__((ext_vector_type(4))) unsigned int u32x4;

constexpr float SCALE_L2E = 0.08838834764831845f * 1.4426950408889634f; // (1/sqrt(128))*log2(e)

__device__ __forceinline__ unsigned short f2bf(float f) {
  unsigned int u = __float_as_uint(f);
  u = (u + 0x7FFFu + ((u >> 16) & 1u)) >> 16;
  return (unsigned short)u;
}

__device__ __forceinline__ void gl_lds16(const void* g, void* l) {
  __builtin_amdgcn_global_load_lds(
      (__attribute__((address_space(1))) void*)const_cast<void*>(g),
      (__attribute__((address_space(3))) void*)l, 16, 0, 0);
}

// ---------------- K0: f32 -> bf16 convert (query + 3 weight matrices) ----------------
__global__ __launch_bounds__(256) void k_convert(
    const float* __restrict__ q, const float* __restrict__ wq,
    const float* __restrict__ wk, const float* __restrict__ wv,
    unsigned short* __restrict__ xb, unsigned short* __restrict__ wb) {
  long i = ((long)blockIdx.x * 256 + threadIdx.x) * 8;
  const float* s; unsigned short* d;
  if (i < 4194304)      { s = q  + i;             d = xb + i; }
  else if (i < 5242880) { s = wq + (i - 4194304); d = wb + (i - 4194304); }
  else if (i < 6291456) { s = wk + (i - 5242880); d = wb + 1048576 + (i - 5242880); }
  else                  { s = wv + (i - 6291456); d = wb + 2097152 + (i - 6291456); }
  float4 a = *(const float4*)s;
  float4 b = *(const float4*)(s + 4);
  us8 r;
  r[0]=f2bf(a.x); r[1]=f2bf(a.y); r[2]=f2bf(a.z); r[3]=f2bf(a.w);
  r[4]=f2bf(b.x); r[5]=f2bf(b.y); r[6]=f2bf(b.z); r[7]=f2bf(b.w);
  *(us8*)d = r;
}

// ---------------- K1: projection GEMM  C = X @ W^T + b  (z selects q/k/v) ----------------
// z==0 (q): sign twist, row-major out. z==1 (k): row-major out (repacked later).
// z==2 (v): written DIRECTLY in PV A-fragment order:
//   vfrag[bh][dt][mc][lane][j]  where lane=(d&31)+32*((m>>3)&1), j=m&7, dt=d>>5, mc=m>>4.
__global__ __launch_bounds__(256) void k_proj(
    const unsigned short* __restrict__ xb, const unsigned short* __restrict__ wb,
    const float* __restrict__ bq, const float* __restrict__ bk, const float* __restrict__ bv,
    unsigned short* __restrict__ oq, unsigned short* __restrict__ ok_, unsigned short* __restrict__ vt) {
  __shared__ unsigned short As[4096]; // 128 rows x 32 k
  __shared__ unsigned short Bs[4096];
  const int t = threadIdx.x;
  const int wave = t >> 6, lane = t & 63;
  const int lrow = lane & 15, grp = lane >> 4;
  const int z = blockIdx.z;
  const unsigned short* w = wb + (size_t)z * 1048576;
  const float* bias = (z == 0) ? bq : ((z == 1) ? bk : bv);

  const unsigned short* asrc = xb + ((size_t)(blockIdx.y * 128 + (t >> 2)) * 1024 + (t & 3) * 8);
  const unsigned short* bsrc = w  + ((size_t)(blockIdx.x * 128 + (t >> 2)) * 1024 + (t & 3) * 8);

  f32x4 acc[4][4] = {};
  for (int kt = 0; kt < 32; ++kt) {
    gl_lds16(asrc + kt*32,              &As[t*8]);
    gl_lds16(asrc + kt*32 + 64*1024,    &As[2048 + t*8]);
    gl_lds16(bsrc + kt*32,              &Bs[t*8]);
    gl_lds16(bsrc + kt*32 + 64*1024,    &Bs[2048 + t*8]);
    __syncthreads();
    const int wr = wave >> 1, wc = wave & 1;
    bf16x8 af[4], bf[4];
#pragma unroll
    for (int mf = 0; mf < 4; ++mf)
      af[mf] = *(const bf16x8*)&As[(wr*64 + mf*16 + lrow)*32 + grp*8];
#pragma unroll
    for (int nf = 0; nf < 4; ++nf)
      bf[nf] = *(const bf16x8*)&Bs[(wc*64 + nf*16 + lrow)*32 + grp*8];
#pragma unroll
    for (int mf = 0; mf < 4; ++mf)
#pragma unroll
      for (int nf = 0; nf < 4; ++nf)
        acc[mf][nf] = __builtin_amdgcn_mfma_f32_16x16x32_bf16(af[mf], bf[nf], acc[mf][nf], 0, 0, 0);
    __syncthreads();
  }
  const int wr = wave >> 1, wc = wave & 1;
  if (z == 2) {
#pragma unroll
    for (int nf = 0; nf < 4; ++nf) {
      const int col = blockIdx.x*128 + wc*64 + nf*16 + lrow;   // global channel (h,d)
      const int h = col >> 7, dd = col & 127;
      const int dt = dd >> 5, lv = dd & 31;
      const float bsv = bias[col];
#pragma unroll
      for (int mf = 0; mf < 4; ++mf) {
        const int r0 = blockIdx.y*128 + wr*64 + mf*16 + grp*4;
        const int bb = r0 >> 11, m = r0 & 2047;
        const int mc = m >> 4, him = (m >> 3) & 1, j0 = m & 7;
        bf16x4 pv;
#pragma unroll
        for (int i = 0; i < 4; ++i) pv[i] = (__bf16)(acc[mf][nf][i] + bsv);
        const size_t off = ((((size_t)((bb*8 + h)*4 + dt))*128 + mc)*64 + lv + 32*him)*8 + j0;
        *(bf16x4*)&vt[off] = pv;
      }
    }
  } else {
    unsigned short* dst = (z == 0) ? oq : ok_;
    const float sign = (z == 0 && (lane & 7) >= 4) ? -1.0f : 1.0f;
#pragma unroll
    for (int nf = 0; nf < 4; ++nf) {
      const int col = blockIdx.x*128 + wc*64 + nf*16 + lrow;
      const float bsv = bias[col];
#pragma unroll
      for (int mf = 0; mf < 4; ++mf)
#pragma unroll
        for (int i = 0; i < 4; ++i) {
          const int row = blockIdx.y*128 + wr*64 + mf*16 + grp*4 + i;
          dst[(size_t)row*1024 + col] = f2bf((acc[mf][nf][i] + bsv) * sign);
        }
    }
  }
}

// ---------------- K2: repack K row-major -> QK A-fragment order ----------------
// kfrag[bh][mtile][kc][lane][j]: lane=(m&31)+32*((k>>3)&1), j=k&7, mtile=m>>5, kc=k>>4.
__global__ __launch_bounds__(256) void k_repack(const unsigned short* __restrict__ kws,
                                                unsigned short* __restrict__ kfrag) {
  const int c = blockIdx.x * 256 + threadIdx.x;   // 0..524287 (us8 chunks)
  const int lane = c & 63, kc = (c >> 6) & 7, mtile = (c >> 9) & 63, bh = c >> 15;
  const int b = bh >> 3, h = bh & 7;
  const int m = mtile*32 + (lane & 31);
  const int kd = kc*16 + (lane >> 5)*8;
  us8 v = *(const us8*)&kws[((size_t)(b*2048 + m))*1024 + h*128 + kd];
  *(us8*)&kfrag[(size_t)c * 8] = v;
}

// ---------------- K3: fused attention out + rowsum ----------------
// Round-9 math (verified), restructured for block-level overlap: QBLK=64, 512 blocks
// of 4 waves (wave = mg*2+lg: mg = m-half of the 64-m tile, lg = 32-l slice), so
// 2 INDEPENDENT blocks co-reside per CU (not barrier-synced -> one block's MFMA
// overlaps the other's softmax/barrier). Epilogue slab overlaid on the K/V staging
// pool (all staged-data reads complete before epilogue) -> LDS ~64 KB/block.
__global__ __launch_bounds__(256) void k_attn_out(
    const unsigned short* __restrict__ qw, const unsigned short* __restrict__ kfrag,
    const unsigned short* __restrict__ vfrag, float* __restrict__ outp,
    float* __restrict__ rsw) {
  __shared__ __align__(16) char pool[65536];
  unsigned short (*KsL)[8192] = (unsigned short(*)[8192])pool;             // [2][8192] us, 32 KB
  unsigned short (*VsL)[8192] = (unsigned short(*)[8192])(pool + 32768);   // [2][8192] us, 32 KB
  float (*slab)[32][36] = (float(*)[32][36])pool;                          // [4][32][36] f32, 18.4 KB (overlay)
  float (*rsred)[32] = (float(*)[32])(pool + 61440);                       // [4][32] (overlay, post-loop)
  float* invb = (float*)(pool + 62464);                                    // [64]

  const int bid = blockIdx.x;
  const int xcd = bid & 7, r_ = bid >> 3;
  const int bh = (xcd << 1) | (r_ & 1);    // 2 bh per XCD -> K/V L2-resident
  const int lt = r_ >> 1;                  // 0..31 (64-l tile)
  const int b = bh >> 3, h = bh & 7;
  const int t = threadIdx.x;
  const int wave = t >> 6, lane = t & 63;
  const int mg = wave >> 1, lg = wave & 1;
  const int lm = lane & 31, hi = lane >> 5;

  // Q fragments (B-operand: col = lane&31 = l, k = kc*16 + 8*hi + j). Loaded once.
  bf16x8 qf[8];
  {
    const unsigned short* qp = qw + ((size_t)(b*2048 + lt*64 + lg*32 + lm))*1024
                                  + (size_t)h*128 + hi*8;
#pragma unroll
    for (int kc = 0; kc < 8; ++kc) qf[kc] = *(const bf16x8*)(qp + kc*16);
  }

  const unsigned short* kbp = kfrag + (size_t)bh*262144;
  const unsigned short* vbp = vfrag + (size_t)bh*262144;
  const int vdt = (t >> 6) & 3, vln = (t & 63) * 8;   // V staging decomposition

  auto STAGE = [&](int buf, int it) {
    // K tile: mtiles {it, 32+it} (32m x 128k each = 4096 us = 512 x 8us chunks)
#pragma unroll
    for (int q = 0; q < 2; ++q)
#pragma unroll
      for (int p = 0; p < 2; ++p)
        gl_lds16(kbp + (q*32 + it)*4096 + (p*256 + t)*8, &KsL[buf][q*4096 + (p*256 + t)*8]);
    // V tile: halves s (= mg consumer), windows w2; mc = s*64 + it*2 + w2
#pragma unroll
    for (int s = 0; s < 2; ++s)
#pragma unroll
      for (int w2 = 0; w2 < 2; ++w2)
        gl_lds16(vbp + vdt*65536 + (s*64 + it*2 + w2)*512 + vln,
                 &VsL[buf][s*4096 + w2*2048 + vdt*512 + vln]);
  };

  f32x16 oacc[4] = {};
  float rs = 0.f;

  STAGE(0, 0);
  __syncthreads();

  for (int it = 0; it < 32; ++it) {
    const int cur = it & 1;
    if (it + 1 < 32) STAGE(cur ^ 1, it + 1);

    bf16x8 kf[8];
#pragma unroll
    for (int kc = 0; kc < 8; ++kc)
      kf[kc] = *(const bf16x8*)&KsL[cur][mg*4096 + kc*512 + lane*8];
    f32x16 s = {};
#pragma unroll
    for (int kc = 0; kc < 8; ++kc)
      s = __builtin_amdgcn_mfma_f32_32x32x16_bf16(kf[kc], qf[kc], s, 0, 0, 0);

    bf16x8 vf[8];
#pragma unroll
    for (int w2 = 0; w2 < 2; ++w2)
#pragma unroll
      for (int dt = 0; dt < 4; ++dt)
        vf[w2*4 + dt] = *(const bf16x8*)&VsL[cur][mg*4096 + w2*2048 + dt*512 + lane*8];

    float e[16];
#pragma unroll
    for (int r = 0; r < 16; ++r) e[r] = __builtin_amdgcn_exp2f(s[r] * SCALE_L2E);
    float ps = 0.f;
#pragma unroll
    for (int r = 0; r < 16; ++r) ps += e[r];
    rs += ps;

    bf16x8 pf[2];
#pragma unroll
    for (int w2 = 0; w2 < 2; ++w2) {
      unsigned a0, a1, b0, b1;
      asm("v_cvt_pk_bf16_f32 %0, %1, %2" : "=v"(a0) : "v"(e[8*w2+0]), "v"(e[8*w2+1]));
      asm("v_cvt_pk_bf16_f32 %0, %1, %2" : "=v"(a1) : "v"(e[8*w2+2]), "v"(e[8*w2+3]));
      asm("v_cvt_pk_bf16_f32 %0, %1, %2" : "=v"(b0) : "v"(e[8*w2+4]), "v"(e[8*w2+5]));
      asm("v_cvt_pk_bf16_f32 %0, %1, %2" : "=v"(b1) : "v"(e[8*w2+6]), "v"(e[8*w2+7]));
      asm("v_permlane32_swap_b32 %0, %1" : "+v"(a0), "+v"(b0));
      asm("v_permlane32_swap_b32 %0, %1" : "+v"(a1), "+v"(b1));
      u32x4 pw = {a0, a1, b0, b1};
      pf[w2] = __builtin_bit_cast(bf16x8, pw);
    }

#pragma unroll
    for (int dt = 0; dt < 4; ++dt) {
      oacc[dt] = __builtin_amdgcn_mfma_f32_32x32x16_bf16(vf[dt],     pf[0], oacc[dt], 0, 0, 0);
      oacc[dt] = __builtin_amdgcn_mfma_f32_32x32x16_bf16(vf[4 + dt], pf[1], oacc[dt], 0, 0, 0);
    }
    __syncthreads();   // next tile landed (vmcnt) + all reads of cur done
  }

  // ---- epilogue: rowsum merge, then 4-phase O reduction over the 2 m-halves ----
  // (pool reuse is safe: loop-final barrier means all KsL/VsL reads are complete)
  rs += __shfl_xor(rs, 32, 64);
  if (lane < 32) rsred[wave][lm] = rs;
  __syncthreads();
  if (t < 64) {
    const int tlg = t >> 5, tl = t & 31;
    const float tot = rsred[tlg][tl] + rsred[2 + tlg][tl];
    rsw[(size_t)bh*2048 + lt*64 + t] = tot;
    invb[t] = 1.0f / tot;
  }

#pragma unroll
  for (int dt = 0; dt < 4; ++dt) {
    __syncthreads();
#pragma unroll
    for (int c = 0; c < 4; ++c) {
      float4 v4 = { oacc[dt][4*c + 0], oacc[dt][4*c + 1], oacc[dt][4*c + 2], oacc[dt][4*c + 3] };
      *(float4*)&slab[wave][lm][8*c + 4*hi] = v4;
    }
    __syncthreads();
    const int lgg = t >> 7, idx = t & 127;
    const int l = idx >> 2, d0 = (idx & 3) * 8;
    const float iv = invb[lgg*32 + l];
    float4 x0 = *(const float4*)&slab[lgg][l][d0];        // mg=0 wave for this lg
    float4 x1 = *(const float4*)&slab[lgg][l][d0 + 4];
    float4 y0 = *(const float4*)&slab[2 + lgg][l][d0];    // mg=1 wave
    float4 y1 = *(const float4*)&slab[2 + lgg][l][d0 + 4];
    float4 o0 = { (x0.x + y0.x)*iv, (x0.y + y0.y)*iv, (x0.z + y0.z)*iv, (x0.w + y0.w)*iv };
    float4 o1 = { (x1.x + y1.x)*iv, (x1.y + y1.y)*iv, (x1.z + y1.z)*iv, (x1.w + y1.w)*iv };
    float* op = outp + ((size_t)(b*2048 + lt*64 + lgg*32 + l))*1024 + h*128 + dt*32 + d0;
    *(float4*)op = o0;
    *(float4*)(op + 4) = o1;
  }
}

// ---------------- K4: head-mean attention weights (LDS-staged GEMM version) ----------------
__global__ __launch_bounds__(256) void k_attn_mean(
    const unsigned short* __restrict__ qw, const unsigned short* __restrict__ kb,
    const float* __restrict__ rsw, float* __restrict__ meanp) {
  __shared__ unsigned short Qs[128*128];   // 32 KB
  __shared__ unsigned short Ks[128*128];   // 32 KB
  __shared__ float inv_s[8*128];           // 4 KB
  const int mt = blockIdx.x;   // 0..15
  const int lt = blockIdx.y;   // 0..15
  const int b  = blockIdx.z;   // 0..1
  const int t = threadIdx.x;
  const int wave = t >> 6, lane = t & 63;
  const int lrow = lane & 15, grp = lane >> 4;
  const int wl = wave >> 1, wm = wave & 1;
  const int trow = t >> 4;     // 0..15 (staging row-within-16)
  const int tcol = t & 15;     // staging 16B-granule column

  for (int idx = t; idx < 1024; idx += 256) {
    int hh = idx >> 7, ll = idx & 127;
    inv_s[idx] = 1.0f / rsw[(size_t)(b*8 + hh)*2048 + lt*128 + ll];
  }

  f32x4 acc[4][4] = {};

  for (int h = 0; h < 8; ++h) {
    __syncthreads();
    const unsigned short* qbase = qw + ((size_t)(b*2048 + lt*128) * 1024 + h*128);
    const unsigned short* kbase = kb + ((size_t)(b*2048 + mt*128) * 1024 + h*128);
#pragma unroll
    for (int i = 0; i < 8; ++i) {
      const int row = i*16 + trow;
      const int sc = (tcol ^ (row & 7)) * 8;
      gl_lds16(qbase + (size_t)row*1024 + sc, &Qs[i*2048 + t*8]);
      gl_lds16(kbase + (size_t)row*1024 + sc, &Ks[i*2048 + t*8]);
    }
    __syncthreads();

    f32x4 s[4][4] = {};
#pragma unroll
    for (int ks = 0; ks < 4; ++ks) {
      bf16x8 af[4], bf[4];
#pragma unroll
      for (int lf = 0; lf < 4; ++lf) {
        const int row = wl*64 + lf*16 + lrow;
        af[lf] = *(const bf16x8*)&Qs[row*128 + ((ks*32 + grp*8) ^ ((row & 7) << 3))];
      }
#pragma unroll
      for (int mf = 0; mf < 4; ++mf) {
        const int row = wm*64 + mf*16 + lrow;
        bf[mf] = *(const bf16x8*)&Ks[row*128 + ((ks*32 + grp*8) ^ ((row & 7) << 3))];
      }
#pragma unroll
      for (int lf = 0; lf < 4; ++lf)
#pragma unroll
        for (int mf = 0; mf < 4; ++mf)
          s[lf][mf] = __builtin_amdgcn_mfma_f32_16x16x32_bf16(af[lf], bf[mf], s[lf][mf], 0, 0, 0);
    }
#pragma unroll
    for (int lf = 0; lf < 4; ++lf)
#pragma unroll
      for (int i = 0; i < 4; ++i) {
        const float iv = inv_s[h*128 + wl*64 + lf*16 + grp*4 + i];
#pragma unroll
        for (int mf = 0; mf < 4; ++mf)
          acc[lf][mf][i] += __builtin_amdgcn_exp2f(s[lf][mf][i] * SCALE_L2E) * iv;
      }
  }

#pragma unroll
  for (int lf = 0; lf < 4; ++lf)
#pragma unroll
    for (int i = 0; i < 4; ++i) {
      const int l = lt*128 + wl*64 + lf*16 + grp*4 + i;
      const size_t rowo = (size_t)(b*2048 + l) * 2048;
#pragma unroll
      for (int mf = 0; mf < 4; ++mf)
        meanp[rowo + mt*128 + wm*64 + mf*16 + lrow] = acc[lf][mf][i] * 0.125f;
    }
}

extern "C" void kernel_launch(void* const* d_in, const int* in_sizes, int n_in,
                              void* d_out, int out_size, void* d_ws, size_t ws_size,
                              hipStream_t stream) {
  (void)in_sizes; (void)n_in; (void)out_size; (void)ws_size;
  const float* query = (const float*)d_in[0];
  const float* Wq = (const float*)d_in[1];
  const float* bq = (const float*)d_in[2];
  const float* Wk = (const float*)d_in[3];
  const float* bk = (const float*)d_in[4];
  const float* Wv = (const float*)d_in[5];
  const float* bv = (const float*)d_in[6];
  float* outp  = (float*)d_out;
  float* meanp = outp + 4194304;           // (B,L,DM) then (B,L,L)

  char* ws = (char*)d_ws;
  unsigned short* xb    = (unsigned short*)(ws);              // 8.4 MB
  unsigned short* wb    = (unsigned short*)(ws + 8388608);    // 6.3 MB (Wq,Wk,Wv)
  unsigned short* qws   = (unsigned short*)(ws + 14680064);   // 8.4 MB (sign-twisted q, row-major)
  unsigned short* kws   = (unsigned short*)(ws + 23068672);   // 8.4 MB (k row-major, for mean)
  unsigned short* kfrag = (unsigned short*)(ws + 31457280);   // 8.4 MB (k frag-order)
  unsigned short* vfrag = (unsigned short*)(ws + 39845888);   // 8.4 MB (v frag-order)
  float*          rsw   = (float*)(ws + 48234496);            // 128 KB rowsums

  k_convert<<<3584, 256, 0, stream>>>(query, Wq, Wk, Wv, xb, wb);
  k_proj<<<dim3(8, 32, 3), 256, 0, stream>>>(xb, wb, bq, bk, bv, qws, kws, vfrag);
  k_repack<<<2048, 256, 0, stream>>>(kws, kfrag);
  k_attn_out<<<512, 256, 0, stream>>>(qws, kfrag, vfrag, outp, rsw);
  k_attn_mean<<<dim3(16, 16, 2), 256, 0, stream>>>(qws, kws, rsw, meanp);
}